// Round 6
// baseline (745.019 us; speedup 1.0000x reference)
//
#include <hip/hip_runtime.h>
#include <hip/hip_bf16.h>
#include <math.h>

// Problem constants (match reference setup_inputs)
#define NN   100000
#define NE   1600000
#define FIN  128
#define HID  32
#define NHEADS 4
#define NCLS 10

typedef unsigned int uint32;

__device__ __forceinline__ float bf_lo(uint32 v) {
    return __builtin_bit_cast(float, v << 16);
}
__device__ __forceinline__ float bf_hi(uint32 v) {
    return __builtin_bit_cast(float, v & 0xffff0000u);
}
__device__ __forceinline__ uint32 packbf2(float a, float b) {
    uint32 ua = __builtin_bit_cast(uint32, a);
    uint32 ub = __builtin_bit_cast(uint32, b);
    ua = (ua + 0x7fffu + ((ua >> 16) & 1u)) >> 16;          // RNE
    ub = (ub + 0x7fffu + ((ub >> 16) & 1u)) & 0xffff0000u;  // RNE, keep high
    return ua | ub;
}

__device__ __forceinline__ void fma8(float* acc, uint4 v, float w) {
    acc[0] = fmaf(bf_lo(v.x), w, acc[0]);
    acc[1] = fmaf(bf_hi(v.x), w, acc[1]);
    acc[2] = fmaf(bf_lo(v.y), w, acc[2]);
    acc[3] = fmaf(bf_hi(v.y), w, acc[3]);
    acc[4] = fmaf(bf_lo(v.z), w, acc[4]);
    acc[5] = fmaf(bf_hi(v.z), w, acc[5]);
    acc[6] = fmaf(bf_lo(v.w), w, acc[6]);
    acc[7] = fmaf(bf_hi(v.w), w, acc[7]);
}

// ---------------------------------------------------------------------------
// CSR build kernels
// ---------------------------------------------------------------------------
__global__ void zero_i32(int* __restrict__ p, int n) {
    int i = blockIdx.x * blockDim.x + threadIdx.x;
    if (i < n) p[i] = 0;
}

// histogram + per-edge rank in one pass: the atomic's return value IS the
// rank of edge j within its dst segment. 4 edges/thread for atomic ILP.
__global__ void hist_rank_kernel(const int* __restrict__ dst, int* __restrict__ cnt,
                                 int* __restrict__ rank, int e) {
    const int t0 = blockIdx.x * (blockDim.x * 4) + threadIdx.x;
    int d[4];
    bool a[4];
#pragma unroll
    for (int k = 0; k < 4; ++k) {
        const int j = t0 + k * 256;
        a[k] = (j < e);
        d[k] = a[k] ? dst[j] : 0;
    }
    int r[4];
#pragma unroll
    for (int k = 0; k < 4; ++k)
        if (a[k]) r[k] = atomicAdd(&cnt[d[k]], 1);
#pragma unroll
    for (int k = 0; k < 4; ++k) {
        const int j = t0 + k * 256;
        if (a[k]) rank[j] = r[k];
    }
}

__global__ void scan_block_sums(const int* __restrict__ cnt, int* __restrict__ bsum, int n) {
    __shared__ int sm[256];
    int i = blockIdx.x * 256 + threadIdx.x;
    int v = (i < n) ? cnt[i] : 0;
    sm[threadIdx.x] = v;
    __syncthreads();
    for (int off = 128; off > 0; off >>= 1) {
        if (threadIdx.x < off) sm[threadIdx.x] += sm[threadIdx.x + off];
        __syncthreads();
    }
    if (threadIdx.x == 0) bsum[blockIdx.x] = sm[0];
}

__global__ void scan_single(const int* __restrict__ bsum, int* __restrict__ boff, int nb) {
    __shared__ int sm[512];
    int t = threadIdx.x;
    int v = (t < nb) ? bsum[t] : 0;
    sm[t] = v;
    __syncthreads();
    for (int off = 1; off < 512; off <<= 1) {
        int u = (t >= off) ? sm[t - off] : 0;
        __syncthreads();
        sm[t] += u;
        __syncthreads();
    }
    if (t < nb) boff[t] = sm[t] - v;   // exclusive
}

__global__ void scan_final(const int* __restrict__ cnt, const int* __restrict__ boff,
                           int* __restrict__ rowptr, int n) {
    __shared__ int sm[256];
    int i = blockIdx.x * 256 + threadIdx.x;
    int v = (i < n) ? cnt[i] : 0;
    sm[threadIdx.x] = v;
    __syncthreads();
    for (int off = 1; off < 256; off <<= 1) {
        int u = (threadIdx.x >= off) ? sm[threadIdx.x - off] : 0;
        __syncthreads();
        sm[threadIdx.x] += u;
        __syncthreads();
    }
    int incl = sm[threadIdx.x];
    int excl = incl - v;
    if (i < n) rowptr[i] = boff[blockIdx.x] + excl;
    if (i == n - 1) rowptr[n] = boff[blockIdx.x] + incl;  // == E
}

// atomic-free scatter: position = rowptr[dst] + rank. 4 edges/thread.
__global__ void scatter_kernel(const int* __restrict__ src, const int* __restrict__ dst,
                               const int* __restrict__ rank, const int* __restrict__ rowptr,
                               int* __restrict__ esrc, int e) {
    const int t0 = blockIdx.x * (blockDim.x * 4) + threadIdx.x;
#pragma unroll
    for (int k = 0; k < 4; ++k) {
        const int j = t0 + k * 256;
        if (j < e) {
            const int d = dst[j];
            esrc[rowptr[d] + rank[j]] = src[j];
        }
    }
}

// ---------------------------------------------------------------------------
// LDS-tiled GEMM + fused attention-logit epilogue.
//   Outb (bf16-packed)  = RNE(X @ W)                [N, FOUT/2 uints]
//   alS[n,h] = sum_c h[n,h,c]*a_src[h,c]  (fp32, exact — from acc registers)
//   alD[n,h] = sum_c h[n,h,c]*a_dst[h,c]
// As rows padded to 132 floats (16B-aligned rows -> ds_read_b128 A reads).
// ---------------------------------------------------------------------------
template <int FOUT, int H>
__global__ __launch_bounds__(256) void gemm_tiled(const float* __restrict__ X,
                                                  const float* __restrict__ Wm,
                                                  const float* __restrict__ a_s,
                                                  const float* __restrict__ a_d,
                                                  float* __restrict__ alS,
                                                  float* __restrict__ alD,
                                                  uint32* __restrict__ Outb, int n) {
    constexpr int K   = 128;
    constexpr int KC  = 32;
    constexpr int MT  = 128;
    constexpr int CPT = FOUT / 16;            // 8 (FOUT=128) or 2 (FOUT=32)
    constexpr int C   = FOUT / H;             // 32
    constexpr int TPH = 16 / H;               // tx-threads per head: 4 or 16
    __shared__ __align__(16) float As[KC][132];   // row stride 132 -> rows 16B aligned
    __shared__ __align__(16) float Bs[KC][FOUT];

    const int t   = threadIdx.x;
    const int tx  = t & 15;
    const int ty  = t >> 4;
    const int row0 = blockIdx.x * MT;

    float acc[8][CPT];
#pragma unroll
    for (int i = 0; i < 8; ++i)
#pragma unroll
        for (int j = 0; j < CPT; ++j) acc[i][j] = 0.f;

    for (int kc = 0; kc < K; kc += KC) {
#pragma unroll
        for (int i = 0; i < 4; ++i) {
            const int l  = t + i * 256;
            const int ar = l >> 3;
            const int af = l & 7;
            int grow = row0 + ar;
            if (grow >= n) grow = n - 1;
            const float4 v = *(const float4*)(X + (size_t)grow * K + kc + af * 4);
            As[af * 4 + 0][ar] = v.x;
            As[af * 4 + 1][ar] = v.y;
            As[af * 4 + 2][ar] = v.z;
            As[af * 4 + 3][ar] = v.w;
        }
        constexpr int BF4 = KC * FOUT / 4;
#pragma unroll
        for (int i = 0; i < BF4 / 256; ++i) {
            const int l   = t + i * 256;
            const int br  = l / (FOUT / 4);
            const int bc4 = l % (FOUT / 4);
            const float4 v = *(const float4*)(Wm + (size_t)(kc + br) * FOUT + bc4 * 4);
            *(float4*)&Bs[br][bc4 * 4] = v;
        }
        __syncthreads();

#pragma unroll 8
        for (int k = 0; k < KC; ++k) {
            const float4 a0 = *(const float4*)&As[k][ty * 8];
            const float4 a1 = *(const float4*)&As[k][ty * 8 + 4];
            const float a[8] = {a0.x, a0.y, a0.z, a0.w, a1.x, a1.y, a1.z, a1.w};
            float b[CPT];
            if constexpr (CPT == 8) {
                const float4 b0 = *(const float4*)&Bs[k][tx * 8];
                const float4 b1 = *(const float4*)&Bs[k][tx * 8 + 4];
                b[0] = b0.x; b[1] = b0.y; b[2] = b0.z; b[3] = b0.w;
                b[4] = b1.x; b[5] = b1.y; b[6] = b1.z; b[7] = b1.w;
            } else {
                const float2 b0 = *(const float2*)&Bs[k][tx * 2];
                b[0] = b0.x; b[1] = b0.y;
            }
#pragma unroll
            for (int i = 0; i < 8; ++i)
#pragma unroll
                for (int j = 0; j < CPT; ++j)
                    acc[i][j] = fmaf(a[i], b[j], acc[i][j]);
        }
        __syncthreads();
    }

    // ---- fused al epilogue: my cols all belong to head h ----
    const int h     = tx / TPH;
    const int cbase = (tx % TPH) * CPT;       // col offset within head
    float av[CPT], dv[CPT];
#pragma unroll
    for (int j = 0; j < CPT; ++j) {
        av[j] = a_s[h * C + cbase + j];
        dv[j] = a_d[h * C + cbase + j];
    }

#pragma unroll
    for (int i = 0; i < 8; ++i) {
        const int grow = row0 + ty * 8 + i;
        // bf16 store
        if (grow < n) {
            uint32* bp = Outb + ((size_t)grow * FOUT + tx * CPT) / 2;
            if constexpr (CPT == 8) {
                uint4 pb;
                pb.x = packbf2(acc[i][0], acc[i][1]);
                pb.y = packbf2(acc[i][2], acc[i][3]);
                pb.z = packbf2(acc[i][4], acc[i][5]);
                pb.w = packbf2(acc[i][6], acc[i][7]);
                *(uint4*)bp = pb;
            } else {
                *bp = packbf2(acc[i][0], acc[i][1]);
            }
        }
        // partial logit dots + reduce across the TPH lanes sharing this head
        float ps = 0.f, pd = 0.f;
#pragma unroll
        for (int j = 0; j < CPT; ++j) {
            ps = fmaf(acc[i][j], av[j], ps);
            pd = fmaf(acc[i][j], dv[j], pd);
        }
#pragma unroll
        for (int off = 1; off < TPH; off <<= 1) {
            ps += __shfl_xor(ps, off);
            pd += __shfl_xor(pd, off);
        }
        if ((tx % TPH) == 0 && grow < n) {
            alS[(size_t)grow * H + h] = ps;
            alD[(size_t)grow * H + h] = pd;
        }
    }
}

// ---------------------------------------------------------------------------
// group-per-destination aggregation (no-max softmax, bf16 gather) + BN + ELU
//   Out[d, :] = elu(bn( sum_e softmax(e)_e * h[src_e, :] + bias ))
// GL = F/8 lanes per destination (16 for F=128, 4 for F=32): each lane owns
// 8 channels (one uint4 of the bf16 row -> single b128 per edge per group).
// GPW = 64/GL destinations per wave amortize phase-1 lanes and the epilogue.
// Logits are bounded (|e| <~ 10): exp() without max subtraction is safe and
// mathematically identical to max-subtracted softmax.
// ---------------------------------------------------------------------------
template <int H, int C>
__global__ __launch_bounds__(256) void gat_aggregate(
    const uint32* __restrict__ Hb,            // bf16-packed h, row = H*C/2 uints
    const int* __restrict__ rowptr, const int* __restrict__ esrc,
    const float* __restrict__ alS, const float* __restrict__ alD,
    const float* __restrict__ bias, const float* __restrict__ gamma,
    const float* __restrict__ beta, const float* __restrict__ bnmean,
    const float* __restrict__ bnvar, float* __restrict__ Out, int n) {
    constexpr int F   = H * C;                // 128 or 32
    constexpr int RW  = F / 2;                // uints per row: 64 or 16
    constexpr int GL  = F / 8;                // lanes per group: 16 or 4
    constexpr int GPW = 64 / GL;              // dst per wave: 4 or 16
    constexpr int NW  = 4;
    constexpr int DPB = NW * GPW;             // dst per block: 16 or 64
    // plane stride 68: distinct heads land on distinct banks (4h offset);
    // 68*4B = 272B = 17*16B keeps float4 slots 16B-aligned.
    __shared__ __align__(16) float s_ex[NW][H][68];
    __shared__ __align__(16) int   s_src[NW][68];

    const int wave = threadIdx.x >> 6;
    const int lane = threadIdx.x & 63;
    const int g    = lane / GL;
    const int li   = lane % GL;
    const int hsel = (H == 4) ? (li >> 2) : 0;   // head owning channels 8li..8li+7
    const int d    = blockIdx.x * DPB + wave * GPW + g;

    int beg = 0, end = 0;
    if (d < n) { beg = rowptr[d]; end = rowptr[d + 1]; }
    const int deg = end - beg;

    float al_d[H];
#pragma unroll
    for (int h = 0; h < H; ++h) al_d[h] = 0.f;
    if (d < n) {
        if constexpr (H == 4) {
            const float4 v = *(const float4*)(alD + (size_t)d * 4);
            al_d[0] = v.x; al_d[1] = v.y; al_d[2] = v.z; al_d[3] = v.w;
        } else {
            al_d[0] = alD[d];
        }
    }

    float sl[H];
#pragma unroll
    for (int h = 0; h < H; ++h) sl[h] = 0.f;
    float acc[8];
#pragma unroll
    for (int j = 0; j < 8; ++j) acc[j] = 0.f;

    for (int it = 0;; ++it) {
        const int rem = deg - it * GL;        // group-uniform
        int mr = rem;
#pragma unroll
        for (int off = GL; off < 64; off <<= 1)
            mr = max(mr, __shfl_xor(mr, off));
        if (mr <= 0) break;

        // ---- phase 1: one edge per lane (GL edges per dst, GPW dst) ----
        if (li < rem) {
            const int sj = esrc[beg + it * GL + li];
            s_src[wave][lane] = sj;
            if constexpr (H == 4) {
                const float4 av = *(const float4*)(alS + (size_t)sj * 4);
                float t0 = av.x + al_d[0], t1 = av.y + al_d[1];
                float t2 = av.z + al_d[2], t3 = av.w + al_d[3];
                t0 = t0 > 0.f ? t0 : 0.2f * t0;
                t1 = t1 > 0.f ? t1 : 0.2f * t1;
                t2 = t2 > 0.f ? t2 : 0.2f * t2;
                t3 = t3 > 0.f ? t3 : 0.2f * t3;
                const float e0 = __expf(t0), e1 = __expf(t1);
                const float e2 = __expf(t2), e3 = __expf(t3);
                s_ex[wave][0][lane] = e0; s_ex[wave][1][lane] = e1;
                s_ex[wave][2][lane] = e2; s_ex[wave][3][lane] = e3;
                sl[0] += e0; sl[1] += e1; sl[2] += e2; sl[3] += e3;
            } else {
                float t0 = alS[sj] + al_d[0];
                t0 = t0 > 0.f ? t0 : 0.2f * t0;
                const float e0 = __expf(t0);
                s_ex[wave][0][lane] = e0;
                sl[0] += e0;
            }
        }
        __builtin_amdgcn_wave_barrier();

        // ---- phase 2: 4 edges per macro-step, b128 row gather per edge ----
        const int cc = min(GL, mr);           // wave-uniform bound
        for (int e0 = 0; e0 < cc; e0 += 4) {
            const int rr = rem - e0;          // group-uniform
            if (rr > 0) {
                const int4   s4 = *(const int4*)  &s_src[wave][g * GL + e0];
                const float4 w4 = *(const float4*)&s_ex[wave][hsel][g * GL + e0];
                if (rr >= 4) {
                    const uint4 v0 = *(const uint4*)(Hb + (size_t)s4.x * RW + li * 4);
                    const uint4 v1 = *(const uint4*)(Hb + (size_t)s4.y * RW + li * 4);
                    const uint4 v2 = *(const uint4*)(Hb + (size_t)s4.z * RW + li * 4);
                    const uint4 v3 = *(const uint4*)(Hb + (size_t)s4.w * RW + li * 4);
                    fma8(acc, v0, w4.x);
                    fma8(acc, v1, w4.y);
                    fma8(acc, v2, w4.z);
                    fma8(acc, v3, w4.w);
                } else {
                    {
                        const uint4 v = *(const uint4*)(Hb + (size_t)s4.x * RW + li * 4);
                        fma8(acc, v, w4.x);
                    }
                    if (rr > 1) {
                        const uint4 v = *(const uint4*)(Hb + (size_t)s4.y * RW + li * 4);
                        fma8(acc, v, w4.y);
                    }
                    if (rr > 2) {
                        const uint4 v = *(const uint4*)(Hb + (size_t)s4.z * RW + li * 4);
                        fma8(acc, v, w4.z);
                    }
                }
            }
        }
        __builtin_amdgcn_wave_barrier();
    }

    // ---- epilogue: group-local softmax sum, BN, ELU ----
#pragma unroll
    for (int h = 0; h < H; ++h)
#pragma unroll
        for (int off = 1; off < GL; off <<= 1)
            sl[h] += __shfl_xor(sl[h], off);

    const float inv = 1.f / (sl[hsel] + 1e-16f);
    if (d < n) {
        const int c0 = li * 8;
        float y[8];
#pragma unroll
        for (int jj = 0; jj < 8; ++jj) {
            const int c = c0 + jj;
            const float o = acc[jj] * inv;
            float yy = (o + bias[c] - bnmean[c]) * rsqrtf(bnvar[c] + 1e-5f) * gamma[c] + beta[c];
            y[jj] = yy > 0.f ? yy : expm1f(yy);
        }
        float* op = Out + (size_t)d * F + c0;
        *(float4*)(op)     = make_float4(y[0], y[1], y[2], y[3]);
        *(float4*)(op + 4) = make_float4(y[4], y[5], y[6], y[7]);
    }
}

// ---------------------------------------------------------------------------
// classifier: out[n, 10] = H3[n, 32] @ Wc[32, 10] + bc
// ---------------------------------------------------------------------------
__global__ void classifier_kernel(const float* __restrict__ H3, const float* __restrict__ Wc,
                                  const float* __restrict__ bc, float* __restrict__ out, int n) {
    int t  = blockIdx.x * blockDim.x + threadIdx.x;
    int ni = t / NCLS, c = t % NCLS;
    if (ni >= n) return;
    const float* row = H3 + (size_t)ni * HID;
    float a = bc[c];
#pragma unroll
    for (int k = 0; k < HID; ++k) a = fmaf(row[k], Wc[k * NCLS + c], a);
    out[(size_t)ni * NCLS + c] = a;
}

// ---------------------------------------------------------------------------
// launch
// ---------------------------------------------------------------------------
static inline char* align256(char* p) {
    return (char*)(((uintptr_t)p + 255) & ~(uintptr_t)255);
}

extern "C" void kernel_launch(void* const* d_in, const int* in_sizes, int n_in,
                              void* d_out, int out_size, void* d_ws, size_t ws_size,
                              hipStream_t stream) {
    const float* x  = (const float*)d_in[0];
    const int*   ei = (const int*)d_in[1];
    const int N = in_sizes[0] / FIN;
    const int E = in_sizes[1] / 2;
    const int* src = ei;
    const int* dst = ei + E;

    const float *W0 = (const float*)d_in[2],  *as0 = (const float*)d_in[3],
                *ad0 = (const float*)d_in[4], *b0 = (const float*)d_in[5],
                *g0 = (const float*)d_in[6],  *bt0 = (const float*)d_in[7],
                *m0 = (const float*)d_in[8],  *v0 = (const float*)d_in[9];
    const float *W1 = (const float*)d_in[10], *as1 = (const float*)d_in[11],
                *ad1 = (const float*)d_in[12],*b1 = (const float*)d_in[13],
                *g1 = (const float*)d_in[14], *bt1 = (const float*)d_in[15],
                *m1 = (const float*)d_in[16], *v1 = (const float*)d_in[17];
    const float *W2 = (const float*)d_in[18], *as2 = (const float*)d_in[19],
                *ad2 = (const float*)d_in[20],*b2 = (const float*)d_in[21],
                *g2 = (const float*)d_in[22], *bt2 = (const float*)d_in[23],
                *m2 = (const float*)d_in[24], *v2 = (const float*)d_in[25];
    const float *Wc = (const float*)d_in[26], *bc = (const float*)d_in[27];
    float* out = (float*)d_out;

    // workspace carve
    char* p = (char*)d_ws;
    uint32* Abf = (uint32*)p;   p = align256(p + (size_t)N * FIN * 2);   // gemm out bf16
    float* B = (float*)p;       p = align256(p + (size_t)N * FIN * 4);   // layer act out
    float* alS = (float*)p;     p = align256(p + (size_t)N * NHEADS * 4);
    float* alD = (float*)p;     p = align256(p + (size_t)N * NHEADS * 4);
    int* cnt = (int*)p;         p = align256(p + (size_t)N * 4);
    int* rowptr = (int*)p;      p = align256(p + (size_t)(N + 1) * 4);
    int* rank = (int*)p;        p = align256(p + (size_t)E * 4);
    int* esrc = (int*)p;        p = align256(p + (size_t)E * 4);
    int* bsum = (int*)p;        p = align256(p + 512 * 4);
    int* boff = (int*)p;        p = align256(p + 512 * 4);
    (void)ws_size; (void)n_in; (void)out_size;

    const int NB = (N + 255) / 256;
    const int EB4 = (E + 1023) / 1024;   // 4 edges/thread kernels

    // ---- CSR build (once; shared by all 3 layers) ----
    zero_i32<<<NB, 256, 0, stream>>>(cnt, N);
    hist_rank_kernel<<<EB4, 256, 0, stream>>>(dst, cnt, rank, E);
    scan_block_sums<<<NB, 256, 0, stream>>>(cnt, bsum, N);
    scan_single<<<1, 512, 0, stream>>>(bsum, boff, NB);
    scan_final<<<NB, 256, 0, stream>>>(cnt, boff, rowptr, N);
    scatter_kernel<<<EB4, 256, 0, stream>>>(src, dst, rank, rowptr, esrc, E);

    const int GB = (N + 127) / 128;

    // ---- layer 0 ----
    gemm_tiled<128, 4><<<GB, 256, 0, stream>>>(x, W0, as0, ad0, alS, alD, Abf, N);
    gat_aggregate<4, 32><<<(N + 15) / 16, 256, 0, stream>>>(Abf, rowptr, esrc, alS, alD,
                                                            b0, g0, bt0, m0, v0, B, N);
    // ---- layer 1 ----
    gemm_tiled<128, 4><<<GB, 256, 0, stream>>>(B, W1, as1, ad1, alS, alD, Abf, N);
    gat_aggregate<4, 32><<<(N + 15) / 16, 256, 0, stream>>>(Abf, rowptr, esrc, alS, alD,
                                                            b1, g1, bt1, m1, v1, B, N);
    // ---- layer 2 (single head, C=32) ----
    gemm_tiled<32, 1><<<GB, 256, 0, stream>>>(B, W2, as2, ad2, alS, alD, Abf, N);
    gat_aggregate<1, 32><<<(N + 63) / 64, 256, 0, stream>>>(Abf, rowptr, esrc, alS, alD,
                                                            b2, g2, bt2, m2, v2, B, N);
    // ---- classifier ----
    classifier_kernel<<<(N * NCLS + 255) / 256, 256, 0, stream>>>(B, Wc, bc, out, N);
}

// Round 8
// 588.790 us; speedup vs baseline: 1.2653x; 1.2653x over previous
//
#include <hip/hip_runtime.h>
#include <hip/hip_bf16.h>
#include <math.h>

// Problem constants (match reference setup_inputs)
#define NN   100000
#define NE   1600000
#define FIN  128
#define HID  32
#define NHEADS 4
#define NCLS 10

typedef unsigned int uint32;

__device__ __forceinline__ float bf_lo(uint32 v) {
    return __builtin_bit_cast(float, v << 16);
}
__device__ __forceinline__ float bf_hi(uint32 v) {
    return __builtin_bit_cast(float, v & 0xffff0000u);
}
__device__ __forceinline__ uint32 packbf2(float a, float b) {
    uint32 ua = __builtin_bit_cast(uint32, a);
    uint32 ub = __builtin_bit_cast(uint32, b);
    ua = (ua + 0x7fffu + ((ua >> 16) & 1u)) >> 16;          // RNE
    ub = (ub + 0x7fffu + ((ub >> 16) & 1u)) & 0xffff0000u;  // RNE, keep high
    return ua | ub;
}

// ---------------------------------------------------------------------------
// CSR build kernels
// ---------------------------------------------------------------------------
__global__ void zero_i32(int* __restrict__ p, int n) {
    int i = blockIdx.x * blockDim.x + threadIdx.x;
    if (i < n) p[i] = 0;
}

// histogram + per-edge rank in one pass: the atomic's return value IS the
// rank of edge j within its dst segment. 4 edges/thread for atomic ILP.
__global__ void hist_rank_kernel(const int* __restrict__ dst, int* __restrict__ cnt,
                                 int* __restrict__ rank, int e) {
    const int t0 = blockIdx.x * (blockDim.x * 4) + threadIdx.x;
    int d[4];
    bool a[4];
#pragma unroll
    for (int k = 0; k < 4; ++k) {
        const int j = t0 + k * 256;
        a[k] = (j < e);
        d[k] = a[k] ? dst[j] : 0;
    }
    int r[4];
#pragma unroll
    for (int k = 0; k < 4; ++k)
        if (a[k]) r[k] = atomicAdd(&cnt[d[k]], 1);
#pragma unroll
    for (int k = 0; k < 4; ++k) {
        const int j = t0 + k * 256;
        if (a[k]) rank[j] = r[k];
    }
}

__global__ void scan_block_sums(const int* __restrict__ cnt, int* __restrict__ bsum, int n) {
    __shared__ int sm[256];
    int i = blockIdx.x * 256 + threadIdx.x;
    int v = (i < n) ? cnt[i] : 0;
    sm[threadIdx.x] = v;
    __syncthreads();
    for (int off = 128; off > 0; off >>= 1) {
        if (threadIdx.x < off) sm[threadIdx.x] += sm[threadIdx.x + off];
        __syncthreads();
    }
    if (threadIdx.x == 0) bsum[blockIdx.x] = sm[0];
}

__global__ void scan_single(const int* __restrict__ bsum, int* __restrict__ boff, int nb) {
    __shared__ int sm[512];
    int t = threadIdx.x;
    int v = (t < nb) ? bsum[t] : 0;
    sm[t] = v;
    __syncthreads();
    for (int off = 1; off < 512; off <<= 1) {
        int u = (t >= off) ? sm[t - off] : 0;
        __syncthreads();
        sm[t] += u;
        __syncthreads();
    }
    if (t < nb) boff[t] = sm[t] - v;   // exclusive
}

__global__ void scan_final(const int* __restrict__ cnt, const int* __restrict__ boff,
                           int* __restrict__ rowptr, int n) {
    __shared__ int sm[256];
    int i = blockIdx.x * 256 + threadIdx.x;
    int v = (i < n) ? cnt[i] : 0;
    sm[threadIdx.x] = v;
    __syncthreads();
    for (int off = 1; off < 256; off <<= 1) {
        int u = (threadIdx.x >= off) ? sm[threadIdx.x - off] : 0;
        __syncthreads();
        sm[threadIdx.x] += u;
        __syncthreads();
    }
    int incl = sm[threadIdx.x];
    int excl = incl - v;
    if (i < n) rowptr[i] = boff[blockIdx.x] + excl;
    if (i == n - 1) rowptr[n] = boff[blockIdx.x] + incl;  // == E
}

// atomic-free scatter: position = rowptr[dst] + rank. 4 edges/thread.
__global__ void scatter_kernel(const int* __restrict__ src, const int* __restrict__ dst,
                               const int* __restrict__ rank, const int* __restrict__ rowptr,
                               int* __restrict__ esrc, int e) {
    const int t0 = blockIdx.x * (blockDim.x * 4) + threadIdx.x;
#pragma unroll
    for (int k = 0; k < 4; ++k) {
        const int j = t0 + k * 256;
        if (j < e) {
            const int d = dst[j];
            esrc[rowptr[d] + rank[j]] = src[j];
        }
    }
}

// ---------------------------------------------------------------------------
// LDS-tiled GEMM + fused attention-logit epilogue.
//   Outb (bf16-packed)  = RNE(X @ W)                [N, FOUT/2 uints]
//   alS[n,h] = sum_c h[n,h,c]*a_src[h,c]  (fp32, exact — from acc registers)
//   alD[n,h] = sum_c h[n,h,c]*a_dst[h,c]
// As rows padded to 132 floats (16B-aligned rows -> ds_read_b128 A reads).
// ---------------------------------------------------------------------------
template <int FOUT, int H>
__global__ __launch_bounds__(256) void gemm_tiled(const float* __restrict__ X,
                                                  const float* __restrict__ Wm,
                                                  const float* __restrict__ a_s,
                                                  const float* __restrict__ a_d,
                                                  float* __restrict__ alS,
                                                  float* __restrict__ alD,
                                                  uint32* __restrict__ Outb, int n) {
    constexpr int K   = 128;
    constexpr int KC  = 32;
    constexpr int MT  = 128;
    constexpr int CPT = FOUT / 16;            // 8 (FOUT=128) or 2 (FOUT=32)
    constexpr int C   = FOUT / H;             // 32
    constexpr int TPH = 16 / H;               // tx-threads per head: 4 or 16
    __shared__ __align__(16) float As[KC][132];   // row stride 132 -> rows 16B aligned
    __shared__ __align__(16) float Bs[KC][FOUT];

    const int t   = threadIdx.x;
    const int tx  = t & 15;
    const int ty  = t >> 4;
    const int row0 = blockIdx.x * MT;

    float acc[8][CPT];
#pragma unroll
    for (int i = 0; i < 8; ++i)
#pragma unroll
        for (int j = 0; j < CPT; ++j) acc[i][j] = 0.f;

    for (int kc = 0; kc < K; kc += KC) {
#pragma unroll
        for (int i = 0; i < 4; ++i) {
            const int l  = t + i * 256;
            const int ar = l >> 3;
            const int af = l & 7;
            int grow = row0 + ar;
            if (grow >= n) grow = n - 1;
            const float4 v = *(const float4*)(X + (size_t)grow * K + kc + af * 4);
            As[af * 4 + 0][ar] = v.x;
            As[af * 4 + 1][ar] = v.y;
            As[af * 4 + 2][ar] = v.z;
            As[af * 4 + 3][ar] = v.w;
        }
        constexpr int BF4 = KC * FOUT / 4;
#pragma unroll
        for (int i = 0; i < BF4 / 256; ++i) {
            const int l   = t + i * 256;
            const int br  = l / (FOUT / 4);
            const int bc4 = l % (FOUT / 4);
            const float4 v = *(const float4*)(Wm + (size_t)(kc + br) * FOUT + bc4 * 4);
            *(float4*)&Bs[br][bc4 * 4] = v;
        }
        __syncthreads();

#pragma unroll 8
        for (int k = 0; k < KC; ++k) {
            const float4 a0 = *(const float4*)&As[k][ty * 8];
            const float4 a1 = *(const float4*)&As[k][ty * 8 + 4];
            const float a[8] = {a0.x, a0.y, a0.z, a0.w, a1.x, a1.y, a1.z, a1.w};
            float b[CPT];
            if constexpr (CPT == 8) {
                const float4 b0 = *(const float4*)&Bs[k][tx * 8];
                const float4 b1 = *(const float4*)&Bs[k][tx * 8 + 4];
                b[0] = b0.x; b[1] = b0.y; b[2] = b0.z; b[3] = b0.w;
                b[4] = b1.x; b[5] = b1.y; b[6] = b1.z; b[7] = b1.w;
            } else {
                const float2 b0 = *(const float2*)&Bs[k][tx * 2];
                b[0] = b0.x; b[1] = b0.y;
            }
#pragma unroll
            for (int i = 0; i < 8; ++i)
#pragma unroll
                for (int j = 0; j < CPT; ++j)
                    acc[i][j] = fmaf(a[i], b[j], acc[i][j]);
        }
        __syncthreads();
    }

    // ---- fused al epilogue: my cols all belong to head h ----
    const int h     = tx / TPH;
    const int cbase = (tx % TPH) * CPT;       // col offset within head
    float av[CPT], dv[CPT];
#pragma unroll
    for (int j = 0; j < CPT; ++j) {
        av[j] = a_s[h * C + cbase + j];
        dv[j] = a_d[h * C + cbase + j];
    }

#pragma unroll
    for (int i = 0; i < 8; ++i) {
        const int grow = row0 + ty * 8 + i;
        // bf16 store
        if (grow < n) {
            uint32* bp = Outb + ((size_t)grow * FOUT + tx * CPT) / 2;
            if constexpr (CPT == 8) {
                uint4 pb;
                pb.x = packbf2(acc[i][0], acc[i][1]);
                pb.y = packbf2(acc[i][2], acc[i][3]);
                pb.z = packbf2(acc[i][4], acc[i][5]);
                pb.w = packbf2(acc[i][6], acc[i][7]);
                *(uint4*)bp = pb;
            } else {
                *bp = packbf2(acc[i][0], acc[i][1]);
            }
        }
        // partial logit dots + reduce across the TPH lanes sharing this head
        float ps = 0.f, pd = 0.f;
#pragma unroll
        for (int j = 0; j < CPT; ++j) {
            ps = fmaf(acc[i][j], av[j], ps);
            pd = fmaf(acc[i][j], dv[j], pd);
        }
#pragma unroll
        for (int off = 1; off < TPH; off <<= 1) {
            ps += __shfl_xor(ps, off);
            pd += __shfl_xor(pd, off);
        }
        if ((tx % TPH) == 0 && grow < n) {
            alS[(size_t)grow * H + h] = ps;
            alD[(size_t)grow * H + h] = pd;
        }
    }
}

// ---------------------------------------------------------------------------
// wave-per-destination aggregation (no-max softmax, bf16 gather) + BN + ELU
//   Out[d, :] = elu(bn( sum_e softmax(e)_e * h[src_e, :] + bias ))
// Phase-2 (H=4): 8 edges/step, wave-uniform src -> readfirstlane -> SGPR base
// + lane offset; 8 independent 256B loads in flight per step. Inactive edge
// slots carry weight 0, so rounding the loop bound up to x8 is exact.
// Phase-2 (H=1): 4 edges/iteration via 16-lane groups (row is only 64 B).
// Logits are bounded (|e| <~ 10): exp() without max subtraction is safe and
// mathematically identical to max-subtracted softmax.
// NOTE: NW=4 destinations per block — grid must be ceil(n/4) for ALL H.
// ---------------------------------------------------------------------------
template <int H, int C>
__global__ __launch_bounds__(256) void gat_aggregate(
    const uint32* __restrict__ Hb,            // bf16-packed h, row = H*C/2 uints
    const int* __restrict__ rowptr, const int* __restrict__ esrc,
    const float* __restrict__ alS, const float* __restrict__ alD,
    const float* __restrict__ bias, const float* __restrict__ gamma,
    const float* __restrict__ beta, const float* __restrict__ bnmean,
    const float* __restrict__ bnvar, float* __restrict__ Out, int n) {
    constexpr int F  = H * C;                 // 128 or 32
    constexpr int RW = F / 2;                 // uints per row: 64 or 16
    constexpr int NW = 4;
    // stride 68: head-plane h starts at bank 4h -> simultaneous b128 reads of
    // different planes hit disjoint bank quads; slots 64..67 = zero pad.
    __shared__ __align__(16) int   s_src[NW][68];
    __shared__ __align__(16) float s_ex[NW][H][68];

    const int wave = threadIdx.x >> 6;
    const int lane = threadIdx.x & 63;
    const int d    = blockIdx.x * NW + wave;
    if (d >= n) return;                       // only wave-level barriers below

    if (lane < 4) {
        s_src[wave][64 + lane] = 0;
#pragma unroll
        for (int h = 0; h < H; ++h) s_ex[wave][h][64 + lane] = 0.f;
    }
    __builtin_amdgcn_wave_barrier();

    const int beg = rowptr[d], end = rowptr[d + 1];
    float al_d[H], sl[H];
#pragma unroll
    for (int h = 0; h < H; ++h) {
        al_d[h] = alD[(size_t)d * H + h];
        sl[h]   = 0.f;
    }
    float acc0 = 0.f, acc1 = 0.f;
    const int head = (H == 4) ? (lane >> 4) : 0;

    for (int base = beg; base < end; base += 64) {
        const int j   = base + lane;
        const bool act = (j < end);
        int sj = 0;
        float ex[H];
        if (act) {
            sj = esrc[j];
            if constexpr (H == 4) {
                float4 av = *(const float4*)(alS + (size_t)sj * 4);
                float t0 = av.x + al_d[0], t1 = av.y + al_d[1];
                float t2 = av.z + al_d[2], t3 = av.w + al_d[3];
                t0 = t0 > 0.f ? t0 : 0.2f * t0;
                t1 = t1 > 0.f ? t1 : 0.2f * t1;
                t2 = t2 > 0.f ? t2 : 0.2f * t2;
                t3 = t3 > 0.f ? t3 : 0.2f * t3;
                ex[0] = __expf(t0); ex[1] = __expf(t1);
                ex[2] = __expf(t2); ex[3] = __expf(t3);
            } else {
                float t0 = alS[sj] + al_d[0];
                t0 = t0 > 0.f ? t0 : 0.2f * t0;
                ex[0] = __expf(t0);
            }
        } else {
#pragma unroll
            for (int h = 0; h < H; ++h) ex[h] = 0.f;
        }
#pragma unroll
        for (int h = 0; h < H; ++h) {
            s_ex[wave][h][lane] = ex[h];
            sl[h] += ex[h];
        }
        s_src[wave][lane] = sj;
        __builtin_amdgcn_wave_barrier();

        const int cc = min(64, end - base);
        if constexpr (H == 4) {
            const int ccr = (cc + 7) & ~7;    // slots beyond cc have weight 0
            for (int jj = 0; jj < ccr; jj += 8) {
                const int4   sa = *(const int4*)  &s_src[wave][jj];
                const int4   sb = *(const int4*)  &s_src[wave][jj + 4];
                const float4 wa = *(const float4*)&s_ex[wave][head][jj];
                const float4 wb = *(const float4*)&s_ex[wave][head][jj + 4];
                const int b0 = __builtin_amdgcn_readfirstlane(sa.x);
                const int b1 = __builtin_amdgcn_readfirstlane(sa.y);
                const int b2 = __builtin_amdgcn_readfirstlane(sa.z);
                const int b3 = __builtin_amdgcn_readfirstlane(sa.w);
                const int b4 = __builtin_amdgcn_readfirstlane(sb.x);
                const int b5 = __builtin_amdgcn_readfirstlane(sb.y);
                const int b6 = __builtin_amdgcn_readfirstlane(sb.z);
                const int b7 = __builtin_amdgcn_readfirstlane(sb.w);
                const uint32 v0 = Hb[(size_t)b0 * RW + lane];  // SGPR base + voffset
                const uint32 v1 = Hb[(size_t)b1 * RW + lane];
                const uint32 v2 = Hb[(size_t)b2 * RW + lane];
                const uint32 v3 = Hb[(size_t)b3 * RW + lane];
                const uint32 v4 = Hb[(size_t)b4 * RW + lane];
                const uint32 v5 = Hb[(size_t)b5 * RW + lane];
                const uint32 v6 = Hb[(size_t)b6 * RW + lane];
                const uint32 v7 = Hb[(size_t)b7 * RW + lane];
                acc0 = fmaf(bf_lo(v0), wa.x, acc0); acc1 = fmaf(bf_hi(v0), wa.x, acc1);
                acc0 = fmaf(bf_lo(v1), wa.y, acc0); acc1 = fmaf(bf_hi(v1), wa.y, acc1);
                acc0 = fmaf(bf_lo(v2), wa.z, acc0); acc1 = fmaf(bf_hi(v2), wa.z, acc1);
                acc0 = fmaf(bf_lo(v3), wa.w, acc0); acc1 = fmaf(bf_hi(v3), wa.w, acc1);
                acc0 = fmaf(bf_lo(v4), wb.x, acc0); acc1 = fmaf(bf_hi(v4), wb.x, acc1);
                acc0 = fmaf(bf_lo(v5), wb.y, acc0); acc1 = fmaf(bf_hi(v5), wb.y, acc1);
                acc0 = fmaf(bf_lo(v6), wb.z, acc0); acc1 = fmaf(bf_hi(v6), wb.z, acc1);
                acc0 = fmaf(bf_lo(v7), wb.w, acc0); acc1 = fmaf(bf_hi(v7), wb.w, acc1);
            }
        } else {
            const int g  = lane >> 4;      // edge sub-slot
            const int li = lane & 15;      // uint within 16-uint row
            for (int jj = 0; jj < cc; jj += 4) {
                const int   idx = jj + g;              // <= 66, inside padding
                const int   sj2 = s_src[wave][idx];
                const float w   = s_ex[wave][0][idx];  // 0 beyond cc
                const uint32 v  = Hb[(size_t)sj2 * RW + li];
                acc0 = fmaf(bf_lo(v), w, acc0);
                acc1 = fmaf(bf_hi(v), w, acc1);
            }
        }
        __builtin_amdgcn_wave_barrier();
    }

    // reduce exp-sums across the wave (inactive lanes contributed 0)
#pragma unroll
    for (int h = 0; h < H; ++h) {
#pragma unroll
        for (int off = 32; off > 0; off >>= 1) sl[h] += __shfl_xor(sl[h], off);
    }
    float sh;
    if constexpr (H == 4) {
        float a = (head & 1) ? sl[1] : sl[0];
        float b = (head & 1) ? sl[3] : sl[2];
        sh = (head & 2) ? b : a;
    } else {
        sh = sl[0];
        acc0 += __shfl_xor(acc0, 16); acc0 += __shfl_xor(acc0, 32);
        acc1 += __shfl_xor(acc1, 16); acc1 += __shfl_xor(acc1, 32);
    }

    const float inv = 1.f / (sh + 1e-16f);
    const int li  = (F == 128) ? lane : (lane & 15);
    const int c0 = 2 * li, c1 = 2 * li + 1;
    const bool wr = (F == 128) || (lane < 16);
    if (wr) {
        float o0 = acc0 * inv, o1 = acc1 * inv;
        float y0 = (o0 + bias[c0] - bnmean[c0]) * rsqrtf(bnvar[c0] + 1e-5f) * gamma[c0] + beta[c0];
        float y1 = (o1 + bias[c1] - bnmean[c1]) * rsqrtf(bnvar[c1] + 1e-5f) * gamma[c1] + beta[c1];
        y0 = y0 > 0.f ? y0 : expm1f(y0);
        y1 = y1 > 0.f ? y1 : expm1f(y1);
        *(float2*)(Out + (size_t)d * F + c0) = make_float2(y0, y1);
    }
}

// ---------------------------------------------------------------------------
// classifier: out[n, 10] = H3[n, 32] @ Wc[32, 10] + bc
// ---------------------------------------------------------------------------
__global__ void classifier_kernel(const float* __restrict__ H3, const float* __restrict__ Wc,
                                  const float* __restrict__ bc, float* __restrict__ out, int n) {
    int t  = blockIdx.x * blockDim.x + threadIdx.x;
    int ni = t / NCLS, c = t % NCLS;
    if (ni >= n) return;
    const float* row = H3 + (size_t)ni * HID;
    float a = bc[c];
#pragma unroll
    for (int k = 0; k < HID; ++k) a = fmaf(row[k], Wc[k * NCLS + c], a);
    out[(size_t)ni * NCLS + c] = a;
}

// ---------------------------------------------------------------------------
// launch
// ---------------------------------------------------------------------------
static inline char* align256(char* p) {
    return (char*)(((uintptr_t)p + 255) & ~(uintptr_t)255);
}

extern "C" void kernel_launch(void* const* d_in, const int* in_sizes, int n_in,
                              void* d_out, int out_size, void* d_ws, size_t ws_size,
                              hipStream_t stream) {
    const float* x  = (const float*)d_in[0];
    const int*   ei = (const int*)d_in[1];
    const int N = in_sizes[0] / FIN;
    const int E = in_sizes[1] / 2;
    const int* src = ei;
    const int* dst = ei + E;

    const float *W0 = (const float*)d_in[2],  *as0 = (const float*)d_in[3],
                *ad0 = (const float*)d_in[4], *b0 = (const float*)d_in[5],
                *g0 = (const float*)d_in[6],  *bt0 = (const float*)d_in[7],
                *m0 = (const float*)d_in[8],  *v0 = (const float*)d_in[9];
    const float *W1 = (const float*)d_in[10], *as1 = (const float*)d_in[11],
                *ad1 = (const float*)d_in[12],*b1 = (const float*)d_in[13],
                *g1 = (const float*)d_in[14], *bt1 = (const float*)d_in[15],
                *m1 = (const float*)d_in[16], *v1 = (const float*)d_in[17];
    const float *W2 = (const float*)d_in[18], *as2 = (const float*)d_in[19],
                *ad2 = (const float*)d_in[20],*b2 = (const float*)d_in[21],
                *g2 = (const float*)d_in[22], *bt2 = (const float*)d_in[23],
                *m2 = (const float*)d_in[24], *v2 = (const float*)d_in[25];
    const float *Wc = (const float*)d_in[26], *bc = (const float*)d_in[27];
    float* out = (float*)d_out;

    // workspace carve
    char* p = (char*)d_ws;
    uint32* Abf = (uint32*)p;   p = align256(p + (size_t)N * FIN * 2);   // gemm out bf16
    float* B = (float*)p;       p = align256(p + (size_t)N * FIN * 4);   // layer act out
    float* alS = (float*)p;     p = align256(p + (size_t)N * NHEADS * 4);
    float* alD = (float*)p;     p = align256(p + (size_t)N * NHEADS * 4);
    int* cnt = (int*)p;         p = align256(p + (size_t)N * 4);
    int* rowptr = (int*)p;      p = align256(p + (size_t)(N + 1) * 4);
    int* rank = (int*)p;        p = align256(p + (size_t)E * 4);
    int* esrc = (int*)p;        p = align256(p + (size_t)E * 4);
    int* bsum = (int*)p;        p = align256(p + 512 * 4);
    int* boff = (int*)p;        p = align256(p + 512 * 4);
    (void)ws_size; (void)n_in; (void)out_size;

    const int NB = (N + 255) / 256;
    const int EB4 = (E + 1023) / 1024;   // 4 edges/thread kernels

    // ---- CSR build (once; shared by all 3 layers) ----
    zero_i32<<<NB, 256, 0, stream>>>(cnt, N);
    hist_rank_kernel<<<EB4, 256, 0, stream>>>(dst, cnt, rank, E);
    scan_block_sums<<<NB, 256, 0, stream>>>(cnt, bsum, N);
    scan_single<<<1, 512, 0, stream>>>(bsum, boff, NB);
    scan_final<<<NB, 256, 0, stream>>>(cnt, boff, rowptr, N);
    scatter_kernel<<<EB4, 256, 0, stream>>>(src, dst, rank, rowptr, esrc, E);

    const int GB = (N + 127) / 128;
    const int AB = (N + 3) / 4;          // aggregate blocks: 4 dst per block

    // ---- layer 0 ----
    gemm_tiled<128, 4><<<GB, 256, 0, stream>>>(x, W0, as0, ad0, alS, alD, Abf, N);
    gat_aggregate<4, 32><<<AB, 256, 0, stream>>>(Abf, rowptr, esrc, alS, alD,
                                                 b0, g0, bt0, m0, v0, B, N);
    // ---- layer 1 ----
    gemm_tiled<128, 4><<<GB, 256, 0, stream>>>(B, W1, as1, ad1, alS, alD, Abf, N);
    gat_aggregate<4, 32><<<AB, 256, 0, stream>>>(Abf, rowptr, esrc, alS, alD,
                                                 b1, g1, bt1, m1, v1, B, N);
    // ---- layer 2 (single head, C=32) ----
    gemm_tiled<32, 1><<<GB, 256, 0, stream>>>(B, W2, as2, ad2, alS, alD, Abf, N);
    gat_aggregate<1, 32><<<AB, 256, 0, stream>>>(Abf, rowptr, esrc, alS, alD,
                                                 b2, g2, bt2, m2, v2, B, N);
    // ---- classifier ----
    classifier_kernel<<<(N * NCLS + 255) / 256, 256, 0, stream>>>(B, Wc, bc, out, N);
}